// Round 7
// baseline (223.567 us; speedup 1.0000x reference)
//
#include <hip/hip_runtime.h>

typedef unsigned short u16;
typedef __attribute__((ext_vector_type(8))) short short8;   // 8 x bf16 (4 VGPRs)
typedef __attribute__((ext_vector_type(4))) float f32x4;    // MFMA accumulator

__device__ __forceinline__ u16 f2bf(float f){
  union { float f; unsigned u; } v; v.f = f;
  unsigned u = v.u;
  u += 0x7fffu + ((u >> 16) & 1u);   // RNE
  return (u16)(u >> 16);
}
__device__ __forceinline__ float bf2f(u16 h){
  union { unsigned u; float f; } v; v.u = ((unsigned)h) << 16;
  return v.f;
}
// direct global->LDS, 16B/lane; LDS dest is wave-uniform base + lane*16
__device__ __forceinline__ void gload16(const u16* g, u16* l){
  __builtin_amdgcn_global_load_lds(
      (const __attribute__((address_space(1))) unsigned int*)g,
      (__attribute__((address_space(3))) unsigned int*)l, 16, 0, 0);
}

// ---------------------------------------------------------------------------
// Kernel 0b: x [8][256][1024] fp32 -> XT [8][1024][256] bf16 (cast+transpose).
// grid (16 hw-tiles, 4 c-tiles, 8 b).
// ---------------------------------------------------------------------------
__global__ __launch_bounds__(256) void xcast_kernel(
    const float* __restrict__ x, u16* __restrict__ XT)
{
  __shared__ float tile[64][69];
  const int b = blockIdx.z, c0 = blockIdx.y*64, hw0 = blockIdx.x*64;
  const int t = threadIdx.x;
  {
    int r = t >> 2, cs = (t & 3) * 16;    // r = c-local row
    const float* s = x + (size_t)(b*256 + c0 + r)*1024 + hw0 + cs;
    #pragma unroll
    for (int i=0;i<4;i++)
      *(float4*)&tile[r][cs + i*4] = *(const float4*)(s + i*4);
  }
  __syncthreads();
  {
    int hr = t >> 2, cc = (t & 3) * 16;   // hr = hw-local row
    __align__(16) u16 tmp[16];
    #pragma unroll
    for (int i=0;i<16;i++) tmp[i] = f2bf(tile[cc + i][hr]);
    u16* d = XT + (size_t)(b*1024 + hw0 + hr)*256 + c0 + cc;
    *(uint4*)d     = *(uint4*)&tmp[0];
    *(uint4*)(d+8) = *(uint4*)&tmp[8];
  }
}

// ---------------------------------------------------------------------------
// Kernel 1: MFMA projections with FUSED weight cast (fp32 W staged with
// in-flight f2bf).  D[co][q] = sum_c W[co][c] * XT[q][c] (+bias), bf16
// conv-flat out.  proj 0 (theta) pre-scaled by log2(e) -> attn uses raw
// v_exp_f32.  grid (3 proj, 64 qg); block = 128co x 128q, 4 waves.
// ---------------------------------------------------------------------------
__global__ __launch_bounds__(256, 2) void proj_mfma_kernel(
    const u16* __restrict__ XT,
    const float* __restrict__ tw, const float* __restrict__ pw,
    const float* __restrict__ gw,
    const float* __restrict__ tb, const float* __restrict__ pb,
    const float* __restrict__ gb,
    u16* __restrict__ T, u16* __restrict__ PHI, u16* __restrict__ G)
{
  __shared__ __align__(16) u16 Ws[128][136];
  __shared__ __align__(16) u16 Xs[128][136];
  const int proj = blockIdx.x, qg = blockIdx.y;
  const int b = qg >> 3, hw0 = (qg & 7) * 128;
  const int q0 = qg * 128;                        // == b*1024 + hw0
  const float* Wf   = (proj==0) ? tw : (proj==1) ? pw : gw;
  const float* bias = (proj==0) ? tb : (proj==1) ? pb : gb;
  u16* out          = (proj==0) ? T  : (proj==1) ? PHI : G;
  const float scale = (proj==0) ? 1.4426950408889634f : 1.0f;
  const int t = threadIdx.x;
  const int wave = t >> 6, lane = t & 63;
  const int quad = lane >> 4, n16 = lane & 15;

  f32x4 acc[8][2];
  #pragma unroll
  for (int mt=0;mt<8;mt++)
    #pragma unroll
    for (int nt=0;nt<2;nt++){ f32x4 z = {0.f,0.f,0.f,0.f}; acc[mt][nt] = z; }

  for (int c0 = 0; c0 < 256; c0 += 128){
    __syncthreads();
    {
      int row = t >> 1, cb = (t & 1) * 64;
      const float* s1 = Wf + (size_t)row*256 + c0 + cb;
      #pragma unroll
      for (int i=0;i<16;i++){
        float4 v = *(const float4*)(s1 + i*4);
        u16* d = &Ws[row][cb + i*4];
        d[0]=f2bf(v.x); d[1]=f2bf(v.y); d[2]=f2bf(v.z); d[3]=f2bf(v.w);
      }
      const u16* s2 = XT + (size_t)(q0 + row)*256 + c0 + cb;
      #pragma unroll
      for (int i=0;i<8;i++)
        *(uint4*)&Xs[row][cb + i*8] = *(const uint4*)(s2 + i*8);
    }
    __syncthreads();
    #pragma unroll
    for (int kc=0; kc<4; kc++){
      short8 xf[2];
      #pragma unroll
      for (int nt=0;nt<2;nt++)
        xf[nt] = *(const short8*)&Xs[wave*32 + nt*16 + n16][kc*32 + quad*8];
      #pragma unroll
      for (int mt=0;mt<8;mt++){
        short8 wf = *(const short8*)&Ws[mt*16 + n16][kc*32 + quad*8];
        #pragma unroll
        for (int nt=0;nt<2;nt++)
          acc[mt][nt] = __builtin_amdgcn_mfma_f32_16x16x32_bf16(wf, xf[nt], acc[mt][nt], 0, 0, 0);
      }
    }
  }
  #pragma unroll
  for (int mt=0;mt<8;mt++){
    float4 bv = *(const float4*)&bias[mt*16 + quad*4];
    float bb[4] = {bv.x, bv.y, bv.z, bv.w};
    #pragma unroll
    for (int nt=0;nt<2;nt++)
      #pragma unroll
      for (int r=0;r<4;r++)
        out[(size_t)b*131072 + (size_t)(mt*16 + quad*4 + r)*1024
            + hw0 + wave*32 + nt*16 + n16] = f2bf((acc[mt][nt][r] + bb[r]) * scale);
  }
}

// ---------------------------------------------------------------------------
// Kernel 2: bf16 2D transpose, dst[c][r] = src[r][c].  64x64 tiles.
// ---------------------------------------------------------------------------
__global__ __launch_bounds__(256) void transpose_bf_kernel(
    const u16* __restrict__ src, u16* __restrict__ dst, int R, int C)
{
  __shared__ u16 tile[64][72];
  const int t = threadIdx.x;
  const int c0 = blockIdx.x*64, r0 = blockIdx.y*64;
  {
    int rr = t >> 2, cs = (t & 3) * 16;
    const u16* s = src + (size_t)(r0+rr)*C + c0 + cs;
    uint4 a0 = *(const uint4*)s;
    uint4 a1 = *(const uint4*)(s+8);
    *(uint4*)&tile[rr][cs]   = a0;
    *(uint4*)&tile[rr][cs+8] = a1;
  }
  __syncthreads();
  {
    int cc = t >> 2, rs = (t & 3) * 16;
    __align__(16) u16 tmp[16];
    #pragma unroll
    for (int i=0;i<16;i++) tmp[i] = tile[rs+i][cc];
    u16* d = dst + (size_t)(c0+cc)*R + r0 + rs;
    *(uint4*)d     = *(uint4*)&tmp[0];
    *(uint4*)(d+8) = *(uint4*)&tmp[8];
  }
}

// ---------------------------------------------------------------------------
// Kernel 3: flash attention (no-max softmax), key-split S=16, 64-key tiles.
// NEW: 8 waves x 64q (512 thr, 1 block/CU, same 8 waves/CU as before),
// DOUBLE-BUFFERED global_load_lds staging (zero staging VGPRs; swizzled
// global source + linear LDS dest + swizzled reads -- R3 HW-verified):
// prefetch tile t+1 during compute of tile t; one vmcnt(0)+barrier per tile.
// Compute body / Pall P-path / exp2 / setprio / epilogue: R3/R5-verified,
// except Pall rows 72->64 u16 (no pad; slot-XOR spreads banks) so
// LDS = 2x16K(K) + 2x16K(V) + 8x8K(P) = 131072 B exactly.
// Registers: same per-wave footprint as R5 (128 arch + 128 acc = budget).
// ---------------------------------------------------------------------------
__global__ __launch_bounds__(512, 1) void attn_kernel(
    const u16* __restrict__ Tq, const u16* __restrict__ Kk,
    const u16* __restrict__ Vt, u16* __restrict__ Opart,
    float* __restrict__ lpart)
{
  __shared__ __align__(16) u16 Ks[2][8192];   // [buf] 64 keys x 256B rows (swz cols)
  __shared__ __align__(16) u16 Vs[2][8192];   // [buf] 128 d  x 128B rows (swz cols)
  __shared__ __align__(16) u16 Pall[8][4096]; // 8 x [64 q][64]

  const int t = threadIdx.x;
  const int wave = t >> 6, lane = t & 63;
  const int quad = lane >> 4, n16 = lane & 15;
  const int s  = blockIdx.x & 15;
  const int qg = blockIdx.x >> 4;              // 0..15
  const int q0 = qg*512 + wave*64;
  u16* Pw = Pall[wave];
  u16*   Os = Opart + (size_t)s * 1048576;
  float* ls = lpart + (size_t)s * 8192;

  short8 qa[4][4];
  #pragma unroll
  for (int mt=0;mt<4;mt++)
    #pragma unroll
    for (int kc=0;kc<4;kc++)
      qa[mt][kc] = *(const short8*)(Tq + (size_t)(q0 + mt*16 + n16)*128 + kc*32 + quad*8);

  f32x4 o[4][8];
  float lp[4];
  #pragma unroll
  for (int mt=0;mt<4;mt++){
    #pragma unroll
    for (int dt=0;dt<8;dt++){ f32x4 z = {0.f,0.f,0.f,0.f}; o[mt][dt] = z; }
    lp[mt] = 0.f;
  }

  // staging geometry: 16 chunks of 1KB each for K and V; wave w owns chunks
  // w*2..w*2+1.  K chunk = 4 rows of 256B; V chunk = 8 rows of 128B.
  const int ck0   = wave * 2;
  const int rk_l  = lane >> 4;           // K: row-within-chunk
  const int rv_l  = lane >> 3;           // V: row-within-chunk
  const int cbk_l = (lane & 15) * 16;    // K: byte-within-row
  const int cbv_l = (lane & 7) * 16;     // V: byte-within-row
  const int wmask = n16 & 14;
  const int swz   = (n16 & 7) << 4;

  auto STAGE = [&](int bi, int key0){
    #pragma unroll
    for (int i=0;i<2;i++){
      const int ck = ck0 + i;
      const int rk = ck*4 + rk_l;
      gload16(Kk + (size_t)(key0 + rk)*128 + ((cbk_l ^ ((rk & 7) << 4)) >> 1),
              &Ks[bi][ck*512]);
    }
    #pragma unroll
    for (int i=0;i<2;i++){
      const int ck = ck0 + i;
      const int rv = ck*8 + rv_l;
      gload16(Vt + (size_t)rv*8192 + key0 + ((cbv_l ^ ((rv & 7) << 4)) >> 1),
              &Vs[bi][ck*512]);
    }
  };

  STAGE(0, s*512);
  asm volatile("s_waitcnt vmcnt(0)" ::: "memory");
  __syncthreads();

  int bi = 0;
  for (int kt = 0; kt < 8; kt++){
    if (kt < 7) STAGE(bi^1, (s*8 + kt + 1)*64);

    // S^T = K Q^T per 16-key block; exp2; packed b64 P-writes
    #pragma unroll
    for (int ntk=0; ntk<4; ntk++){
      short8 kf[4];
      #pragma unroll
      for (int kc=0;kc<4;kc++)
        kf[kc] = *(const short8*)((const char*)&Ks[bi][0]
                   + ((ntk*16 + n16) << 8) + ((kc*64 + quad*16) ^ swz));
      #pragma unroll
      for (int mtq=0;mtq<4;mtq++){
        f32x4 sa = {0.f,0.f,0.f,0.f};
        #pragma unroll
        for (int kc=0;kc<4;kc++)
          sa = __builtin_amdgcn_mfma_f32_16x16x32_bf16(kf[kc], qa[mtq][kc], sa, 0, 0, 0);
        u16 pb[4];
        #pragma unroll
        for (int r=0;r<4;r++){
          float pe = __builtin_amdgcn_exp2f(sa[r]);
          lp[mtq] += pe;
          pb[r] = f2bf(pe);
        }
        uint2 pk;
        pk.x = ((unsigned)pb[1] << 16) | pb[0];
        pk.y = ((unsigned)pb[3] << 16) | pb[2];
        *(uint2*)(Pw + (mtq*16 + n16)*64 + (((ntk*4 + quad) ^ wmask) << 2)) = pk;
      }
    }

    // drain DS: cross-lane P writes must land before cross-lane P reads
    __builtin_amdgcn_s_waitcnt(0xC07F);

    // O~ += P V, per 32-key half
    #pragma unroll
    for (int kb=0; kb<2; kb++){
      short8 pf[4];
      #pragma unroll
      for (int mtq=0;mtq<4;mtq++)
        pf[mtq] = *(const short8*)(Pw + (mtq*16 + n16)*64 + (((kb*8 + quad*2) ^ wmask) << 2));
      __builtin_amdgcn_s_setprio(1);
      #pragma unroll
      for (int dt=0; dt<8; dt++){
        short8 vfd = *(const short8*)((const char*)&Vs[bi][0]
                       + ((dt*16 + n16) << 7) + ((kb*64 + quad*16) ^ swz));
        #pragma unroll
        for (int mtq=0;mtq<4;mtq++)
          o[mtq][dt] = __builtin_amdgcn_mfma_f32_16x16x32_bf16(pf[mtq], vfd, o[mtq][dt], 0, 0, 0);
      }
      __builtin_amdgcn_s_setprio(0);
    }

    if (kt < 7){
      asm volatile("s_waitcnt vmcnt(0)" ::: "memory");
      __syncthreads();
      bi ^= 1;
    }
  }

  // l: sum across the 4 quads (lane bits 4,5)
  float l[4];
  #pragma unroll
  for (int mt=0;mt<4;mt++){
    float v = lp[mt];
    v += __shfl_xor(v, 16, 64);
    v += __shfl_xor(v, 32, 64);
    l[mt] = v;
  }

  // Epilogue: UNNORMALIZED bf16 partials, lane-packed [row][n16*8+dt]
  // (ch = dt*16+n16); one 16B store per (mt,r), 256B/quad contiguous.
  #pragma unroll
  for (int mt=0;mt<4;mt++){
    #pragma unroll
    for (int r=0;r<4;r++){
      __align__(16) u16 tmp[8];
      #pragma unroll
      for (int dt=0;dt<8;dt++) tmp[dt] = f2bf(o[mt][dt][r]);
      *(uint4*)(Os + (size_t)(q0 + mt*16 + quad*4 + r)*128 + n16*8) = *(uint4*)tmp;
    }
    if (lane < 16)
      ls[q0 + mt*16 + lane] = l[mt];
  }
}

// ---------------------------------------------------------------------------
// Kernel 3b: merge partials -> OmT in CONV layout [q][j], normalized bf16.
// 256 blocks x 32 attn rows so all CUs share the 32 MB reduction.
// attn row = b*1024 + j*8 + hwhi; stored col' encodes ch = (col'&7)*16 +
// (col'>>3); block covers 4 j values x all 1024 hw of one b -> 8B stores.
// ---------------------------------------------------------------------------
__global__ __launch_bounds__(256) void merge_o_kernel(
    const u16* __restrict__ Opart, const float* __restrict__ lpart, int S,
    u16* __restrict__ OmT)
{
  __shared__ u16 Tm[32][136];
  __shared__ float lrow[32];
  const int t = threadIdx.x;
  const int row0 = blockIdx.x * 32;
  const int b  = row0 >> 10;
  const int j0 = (row0 >> 3) & 127;

  if (t < 32){
    float v = 0.f;
    for (int sp=0; sp<S; sp++) v += lpart[sp*8192 + row0 + t];
    lrow[t] = 1.0f / v;
  }

  const int rl = t >> 3;            // 0..31
  const int cb = (t & 7) * 16;      // 0..112
  float acc[16];
  #pragma unroll
  for (int j=0;j<16;j++) acc[j] = 0.f;
  for (int sp=0; sp<S; sp++){
    const u16* p = Opart + (size_t)sp*1048576 + (size_t)(row0 + rl)*128 + cb;
    #pragma unroll
    for (int q=0;q<2;q++){
      ushort4 v = *(const ushort4*)(p + q*8);
      ushort4 w = *(const ushort4*)(p + q*8 + 4);
      acc[q*8+0] += bf2f(v.x); acc[q*8+1] += bf2f(v.y);
      acc[q*8+2] += bf2f(v.z); acc[q*8+3] += bf2f(v.w);
      acc[q*8+4] += bf2f(w.x); acc[q*8+5] += bf2f(w.y);
      acc[q*8+6] += bf2f(w.z); acc[q*8+7] += bf2f(w.w);
    }
  }
  __syncthreads();
  const float inv = lrow[rl];
  #pragma unroll
  for (int j=0;j<16;j++){
    int cp = cb + j;
    int ch = (cp & 7)*16 + (cp >> 3);
    Tm[rl][ch] = f2bf(acc[j] * inv);     // Tm[local attn row][ch]
  }
  __syncthreads();
  // conv-layout output: local row rl = jl*8 + hwhi  (jl = j - j0, 0..3)
  {
    const int hwhi = t >> 5;             // 0..7
    const int chb  = (t & 31) * 4;       // 4 ch per thread
    #pragma unroll
    for (int c=0;c<4;c++){
      int ch = chb + c;
      __align__(8) u16 tmp[4];
      #pragma unroll
      for (int jl=0;jl<4;jl++) tmp[jl] = Tm[jl*8 + hwhi][ch];
      *(uint2*)(OmT + (size_t)(b*1024 + hwhi*128 + ch)*128 + j0) = *(uint2*)tmp;
    }
  }
}

// ---------------------------------------------------------------------------
// Kernel 4: final conv as MFMA + bias + residual (fp32 out).
// D[co][q] = sum_j Ww[co][j] * OmT[q][j];  out = D + Wb + x.
// grid (4 co-tiles, 64 qg); block = 64co x 128q, K=128 single stage.
// ---------------------------------------------------------------------------
__global__ __launch_bounds__(256, 2) void final_mfma_kernel(
    const float* __restrict__ Ww, const float* __restrict__ Wb,
    const u16* __restrict__ OmT, const float* __restrict__ x,
    float* __restrict__ outp)
{
  __shared__ __align__(16) u16 Ws[64][136];
  __shared__ __align__(16) u16 Os[128][136];
  const int co0 = blockIdx.x * 64, qg = blockIdx.y;
  const int b = qg >> 3, hw0 = (qg & 7) * 128;
  const int q0 = qg * 128;                      // == b*1024 + hw0
  const int t = threadIdx.x;
  const int wave = t >> 6, lane = t & 63;
  const int quad = lane >> 4, n16 = lane & 15;

  {
    int row = t >> 2, cbf = (t & 3) * 32;
    const float* sw = Ww + (size_t)(co0 + row)*128 + cbf;
    #pragma unroll
    for (int i=0;i<8;i++){
      float4 v = *(const float4*)(sw + i*4);
      u16* d = &Ws[row][cbf + i*4];
      d[0]=f2bf(v.x); d[1]=f2bf(v.y); d[2]=f2bf(v.z); d[3]=f2bf(v.w);
    }
  }
  {
    int row = t >> 1, cb = (t & 1) * 64;
    const u16* so = OmT + (size_t)(q0 + row)*128 + cb;
    #pragma unroll
    for (int i=0;i<8;i++)
      *(uint4*)&Os[row][cb + i*8] = *(const uint4*)(so + i*8);
  }
  __syncthreads();

  f32x4 acc[4][2];
  #pragma unroll
  for (int mt=0;mt<4;mt++)
    #pragma unroll
    for (int nt=0;nt<2;nt++){ f32x4 z = {0.f,0.f,0.f,0.f}; acc[mt][nt] = z; }

  #pragma unroll
  for (int kc=0; kc<4; kc++){
    short8 xf[2];
    #pragma unroll
    for (int nt=0;nt<2;nt++)
      xf[nt] = *(const short8*)&Os[wave*32 + nt*16 + n16][kc*32 + quad*8];
    #pragma unroll
    for (int mt=0;mt<4;mt++){
      short8 wf = *(const short8*)&Ws[mt*16 + n16][kc*32 + quad*8];
      #pragma unroll
      for (int nt=0;nt<2;nt++)
        acc[mt][nt] = __builtin_amdgcn_mfma_f32_16x16x32_bf16(wf, xf[nt], acc[mt][nt], 0, 0, 0);
    }
  }

  #pragma unroll
  for (int mt=0;mt<4;mt++){
    float4 bv = *(const float4*)&Wb[co0 + mt*16 + quad*4];
    float bb[4] = {bv.x, bv.y, bv.z, bv.w};
    #pragma unroll
    for (int nt=0;nt<2;nt++)
      #pragma unroll
      for (int r=0;r<4;r++){
        size_t idx = (size_t)b*262144 + (size_t)(co0 + mt*16 + quad*4 + r)*1024
                   + hw0 + wave*32 + nt*16 + n16;
        outp[idx] = acc[mt][nt][r] + bb[r] + x[idx];
      }
  }
}

// ---------------------------------------------------------------------------
extern "C" void kernel_launch(void* const* d_in, const int* in_sizes, int n_in,
                              void* d_out, int out_size, void* d_ws, size_t ws_size,
                              hipStream_t stream)
{
  (void)in_sizes; (void)n_in; (void)out_size; (void)ws_size;
  const float* x  = (const float*)d_in[0];
  const float* tw = (const float*)d_in[1];
  const float* tb = (const float*)d_in[2];
  const float* pw = (const float*)d_in[3];
  const float* pb = (const float*)d_in[4];
  const float* gw = (const float*)d_in[5];
  const float* gb = (const float*)d_in[6];
  const float* Ww = (const float*)d_in[7];
  const float* Wb = (const float*)d_in[8];
  float* outp = (float*)d_out;

  char* ws = (char*)d_ws;
  const size_t MB = 1u << 20;
  u16*   Tbf   = (u16*)(ws);            // 2 MB  theta bf16 (log2e-scaled), conv-flat
  u16*   PHIbf = (u16*)(ws + 2*MB);     // 2 MB  phi, conv-flat
  u16*   Gbf   = (u16*)(ws + 4*MB);     // 2 MB  g, conv-flat
  u16*   Kbf   = (u16*)(ws + 6*MB);     // 2 MB  K = phi^T  [8192][128]
  u16*   VTbf  = (u16*)(ws + 8*MB);     // 2 MB  VT = g^T   [128][8192]
  // Lifetime overlays (ws >= 43 MB proven by earlier S=16 runs):
  u16*   Opart = (u16*)(ws + 10*MB);    // 16 x 2 MB bf16 partials (attn+)
  u16*   XT    = (u16*)(ws + 10*MB);    // 4 MB x^T bf16 (dead before attn)
  float* lpart = (float*)(ws + 2*MB);   // 512 KB (PHI dead after transpose)
  u16*   OmT   = (u16*)(ws + 4*MB);     // 2 MB merged O (Gbf dead after transpose)

  xcast_kernel<<<dim3(16, 4, 8), 256, 0, stream>>>(x, XT);
  proj_mfma_kernel<<<dim3(3, 64), 256, 0, stream>>>(XT, tw, pw, gw, tb, pb, gb,
                                                    Tbf, PHIbf, Gbf);
  transpose_bf_kernel<<<dim3(128, 2), 256, 0, stream>>>(PHIbf, Kbf, 128, 8192);
  transpose_bf_kernel<<<dim3(2, 128), 256, 0, stream>>>(Gbf, VTbf, 8192, 128);
  attn_kernel<<<dim3(256), 512, 0, stream>>>(Tbf, Kbf, VTbf, Opart, lpart);
  merge_o_kernel<<<dim3(256), 256, 0, stream>>>(Opart, lpart, 16, OmT);
  final_mfma_kernel<<<dim3(4, 64), 256, 0, stream>>>(Ww, Wb, OmT, x, outp);
}

// Round 8
// 162.328 us; speedup vs baseline: 1.3773x; 1.3773x over previous
//
#include <hip/hip_runtime.h>

typedef unsigned short u16;
typedef __attribute__((ext_vector_type(8))) short short8;   // 8 x bf16 (4 VGPRs)
typedef __attribute__((ext_vector_type(4))) float f32x4;    // MFMA accumulator

__device__ __forceinline__ u16 f2bf(float f){
  union { float f; unsigned u; } v; v.f = f;
  unsigned u = v.u;
  u += 0x7fffu + ((u >> 16) & 1u);   // RNE
  return (u16)(u >> 16);
}
__device__ __forceinline__ float bf2f(u16 h){
  union { unsigned u; float f; } v; v.u = ((unsigned)h) << 16;
  return v.f;
}

// ---------------------------------------------------------------------------
// Kernel 0b: x [8][256][1024] fp32 -> XT [8][1024][256] bf16 (cast+transpose).
// grid (16 hw-tiles, 4 c-tiles, 8 b).
// ---------------------------------------------------------------------------
__global__ __launch_bounds__(256) void xcast_kernel(
    const float* __restrict__ x, u16* __restrict__ XT)
{
  __shared__ float tile[64][69];
  const int b = blockIdx.z, c0 = blockIdx.y*64, hw0 = blockIdx.x*64;
  const int t = threadIdx.x;
  {
    int r = t >> 2, cs = (t & 3) * 16;    // r = c-local row
    const float* s = x + (size_t)(b*256 + c0 + r)*1024 + hw0 + cs;
    #pragma unroll
    for (int i=0;i<4;i++)
      *(float4*)&tile[r][cs + i*4] = *(const float4*)(s + i*4);
  }
  __syncthreads();
  {
    int hr = t >> 2, cc = (t & 3) * 16;   // hr = hw-local row
    __align__(16) u16 tmp[16];
    #pragma unroll
    for (int i=0;i<16;i++) tmp[i] = f2bf(tile[cc + i][hr]);
    u16* d = XT + (size_t)(b*1024 + hw0 + hr)*256 + c0 + cc;
    *(uint4*)d     = *(uint4*)&tmp[0];
    *(uint4*)(d+8) = *(uint4*)&tmp[8];
  }
}

// ---------------------------------------------------------------------------
// Kernel 1: MFMA projections with FUSED weight cast (fp32 W staged with
// in-flight f2bf).  D[co][q] = sum_c W[co][c] * XT[q][c] (+bias), bf16
// conv-flat out.  proj 0 (theta) pre-scaled by log2(e) -> attn uses raw
// v_exp_f32.  grid (3 proj, 64 qg); block = 128co x 128q, 4 waves.
// ---------------------------------------------------------------------------
__global__ __launch_bounds__(256, 2) void proj_mfma_kernel(
    const u16* __restrict__ XT,
    const float* __restrict__ tw, const float* __restrict__ pw,
    const float* __restrict__ gw,
    const float* __restrict__ tb, const float* __restrict__ pb,
    const float* __restrict__ gb,
    u16* __restrict__ T, u16* __restrict__ PHI, u16* __restrict__ G)
{
  __shared__ __align__(16) u16 Ws[128][136];
  __shared__ __align__(16) u16 Xs[128][136];
  const int proj = blockIdx.x, qg = blockIdx.y;
  const int b = qg >> 3, hw0 = (qg & 7) * 128;
  const int q0 = qg * 128;                        // == b*1024 + hw0
  const float* Wf   = (proj==0) ? tw : (proj==1) ? pw : gw;
  const float* bias = (proj==0) ? tb : (proj==1) ? pb : gb;
  u16* out          = (proj==0) ? T  : (proj==1) ? PHI : G;
  const float scale = (proj==0) ? 1.4426950408889634f : 1.0f;
  const int t = threadIdx.x;
  const int wave = t >> 6, lane = t & 63;
  const int quad = lane >> 4, n16 = lane & 15;

  f32x4 acc[8][2];
  #pragma unroll
  for (int mt=0;mt<8;mt++)
    #pragma unroll
    for (int nt=0;nt<2;nt++){ f32x4 z = {0.f,0.f,0.f,0.f}; acc[mt][nt] = z; }

  for (int c0 = 0; c0 < 256; c0 += 128){
    __syncthreads();
    {
      int row = t >> 1, cb = (t & 1) * 64;
      const float* s1 = Wf + (size_t)row*256 + c0 + cb;
      #pragma unroll
      for (int i=0;i<16;i++){
        float4 v = *(const float4*)(s1 + i*4);
        u16* d = &Ws[row][cb + i*4];
        d[0]=f2bf(v.x); d[1]=f2bf(v.y); d[2]=f2bf(v.z); d[3]=f2bf(v.w);
      }
      const u16* s2 = XT + (size_t)(q0 + row)*256 + c0 + cb;
      #pragma unroll
      for (int i=0;i<8;i++)
        *(uint4*)&Xs[row][cb + i*8] = *(const uint4*)(s2 + i*8);
    }
    __syncthreads();
    #pragma unroll
    for (int kc=0; kc<4; kc++){
      short8 xf[2];
      #pragma unroll
      for (int nt=0;nt<2;nt++)
        xf[nt] = *(const short8*)&Xs[wave*32 + nt*16 + n16][kc*32 + quad*8];
      #pragma unroll
      for (int mt=0;mt<8;mt++){
        short8 wf = *(const short8*)&Ws[mt*16 + n16][kc*32 + quad*8];
        #pragma unroll
        for (int nt=0;nt<2;nt++)
          acc[mt][nt] = __builtin_amdgcn_mfma_f32_16x16x32_bf16(wf, xf[nt], acc[mt][nt], 0, 0, 0);
      }
    }
  }
  #pragma unroll
  for (int mt=0;mt<8;mt++){
    float4 bv = *(const float4*)&bias[mt*16 + quad*4];
    float bb[4] = {bv.x, bv.y, bv.z, bv.w};
    #pragma unroll
    for (int nt=0;nt<2;nt++)
      #pragma unroll
      for (int r=0;r<4;r++)
        out[(size_t)b*131072 + (size_t)(mt*16 + quad*4 + r)*1024
            + hw0 + wave*32 + nt*16 + n16] = f2bf((acc[mt][nt][r] + bb[r]) * scale);
  }
}

// ---------------------------------------------------------------------------
// Kernel 2: bf16 2D transpose, dst[c][r] = src[r][c].  64x64 tiles.
// ---------------------------------------------------------------------------
__global__ __launch_bounds__(256) void transpose_bf_kernel(
    const u16* __restrict__ src, u16* __restrict__ dst, int R, int C)
{
  __shared__ u16 tile[64][72];
  const int t = threadIdx.x;
  const int c0 = blockIdx.x*64, r0 = blockIdx.y*64;
  {
    int rr = t >> 2, cs = (t & 3) * 16;
    const u16* s = src + (size_t)(r0+rr)*C + c0 + cs;
    uint4 a0 = *(const uint4*)s;
    uint4 a1 = *(const uint4*)(s+8);
    *(uint4*)&tile[rr][cs]   = a0;
    *(uint4*)&tile[rr][cs+8] = a1;
  }
  __syncthreads();
  {
    int cc = t >> 2, rs = (t & 3) * 16;
    __align__(16) u16 tmp[16];
    #pragma unroll
    for (int i=0;i<16;i++) tmp[i] = tile[rs+i][cc];
    u16* d = dst + (size_t)(c0+cc)*R + r0 + rs;
    *(uint4*)d     = *(uint4*)&tmp[0];
    *(uint4*)(d+8) = *(uint4*)&tmp[8];
  }
}

// ---------------------------------------------------------------------------
// Kernel 3: flash attention (no-max softmax), key-split S=16, 64-key tiles,
// block = 4 waves.  OCCUPANCY RESTRUCTURE of the R5-verified kernel:
// each wave now owns 32 q rows (mtq=2) instead of 64 -> acc 128->64 VGPR,
// qa 64->32, total/wave ~ <=170 = 3 waves/SIMD budget (launch_bounds(256,3));
// LDS trimmed to 52 KB (Ks[64][136] unchanged, Vs pad 72->68, Pall rows
// 64->32 at the IDENTICAL verified 72-u16 stride + wmask XOR) -> 3 blocks/CU,
// 12 waves/CU (was 8): load phases hide under other blocks' compute.
// Staging stays global->VGPR->ds_write (global_load_lds is HBM-traffic
// poison here: R3/R7 measured 5-10x FETCH/WRITE explosion).
// grid 1024: s = bid&15 (key split), qg = bid>>4 (0..63), q0 = qg*128+wave*32.
// ---------------------------------------------------------------------------
__global__ __launch_bounds__(256, 3) void attn_kernel(
    const u16* __restrict__ Tq, const u16* __restrict__ Kk,
    const u16* __restrict__ Vt, u16* __restrict__ Opart,
    float* __restrict__ lpart)
{
  __shared__ __align__(16) u16 Ks[64][136];    // 17408 B
  __shared__ __align__(16) u16 Vs[128][68];    // 17408 B
  __shared__ __align__(16) u16 Pall[4][2304];  // 4 x [32 q][72] = 18432 B

  const int t = threadIdx.x;
  const int wave = t >> 6, lane = t & 63;
  const int quad = lane >> 4, n16 = lane & 15;
  const int s  = blockIdx.x & 15;
  const int qg = blockIdx.x >> 4;              // 0..63
  const int q0 = qg*128 + wave*32;
  u16* Pw = Pall[wave];
  u16*   Os = Opart + (size_t)s * 1048576;
  float* ls = lpart + (size_t)s * 8192;

  short8 qa[2][4];
  #pragma unroll
  for (int mt=0;mt<2;mt++)
    #pragma unroll
    for (int kc=0;kc<4;kc++)
      qa[mt][kc] = *(const short8*)(Tq + (size_t)(q0 + mt*16 + n16)*128 + kc*32 + quad*8);

  f32x4 o[2][8];
  float lp[2];
  #pragma unroll
  for (int mt=0;mt<2;mt++){
    #pragma unroll
    for (int dt=0;dt<8;dt++){ f32x4 z = {0.f,0.f,0.f,0.f}; o[mt][dt] = z; }
    lp[mt] = 0.f;
  }

  const int krow = t >> 2, kcs = (t & 3) * 32;
  const int vrow = t >> 1, vcs = (t & 1) * 32;
  const int wmask = n16 & 14;

  for (int kt = s*8; kt < s*8 + 8; kt++){
    const int key0 = kt * 64;
    __syncthreads();
    #pragma unroll
    for (int i=0;i<4;i++)
      *(uint4*)&Ks[krow][kcs + i*8] =
        *(const uint4*)(Kk + (size_t)(key0 + krow)*128 + kcs + i*8);
    #pragma unroll
    for (int i=0;i<4;i++)
      *(uint4*)&Vs[vrow][vcs + i*8] =
        *(const uint4*)(Vt + (size_t)vrow*8192 + key0 + vcs + i*8);
    __syncthreads();

    // S^T = K Q^T per 16-key block; exp2; packed b64 P-writes
    #pragma unroll
    for (int ntk=0; ntk<4; ntk++){
      short8 kf[4];
      #pragma unroll
      for (int kc=0;kc<4;kc++)
        kf[kc] = *(const short8*)&Ks[ntk*16 + n16][kc*32 + quad*8];
      #pragma unroll
      for (int mtq=0;mtq<2;mtq++){
        f32x4 sa = {0.f,0.f,0.f,0.f};
        #pragma unroll
        for (int kc=0;kc<4;kc++)
          sa = __builtin_amdgcn_mfma_f32_16x16x32_bf16(kf[kc], qa[mtq][kc], sa, 0, 0, 0);
        u16 pb[4];
        #pragma unroll
        for (int r=0;r<4;r++){
          float pe = __builtin_amdgcn_exp2f(sa[r]);
          lp[mtq] += pe;
          pb[r] = f2bf(pe);
        }
        uint2 pk;
        pk.x = ((unsigned)pb[1] << 16) | pb[0];
        pk.y = ((unsigned)pb[3] << 16) | pb[2];
        *(uint2*)(Pw + (mtq*16 + n16)*72 + (((ntk*4 + quad) ^ wmask) << 2)) = pk;
      }
    }

    // drain DS: cross-lane P writes must land before cross-lane P reads
    __builtin_amdgcn_s_waitcnt(0xC07F);

    // O~ += P V, per 32-key half
    #pragma unroll
    for (int kb=0; kb<2; kb++){
      short8 pf[2];
      #pragma unroll
      for (int mtq=0;mtq<2;mtq++)
        pf[mtq] = *(const short8*)(Pw + (mtq*16 + n16)*72 + (((kb*8 + quad*2) ^ wmask) << 2));
      __builtin_amdgcn_s_setprio(1);
      #pragma unroll
      for (int dt=0; dt<8; dt++){
        short8 vfd = *(const short8*)&Vs[dt*16 + n16][kb*32 + quad*8];
        #pragma unroll
        for (int mtq=0;mtq<2;mtq++)
          o[mtq][dt] = __builtin_amdgcn_mfma_f32_16x16x32_bf16(pf[mtq], vfd, o[mtq][dt], 0, 0, 0);
      }
      __builtin_amdgcn_s_setprio(0);
    }
  }

  // l: sum across the 4 quads (lane bits 4,5)
  float l[2];
  #pragma unroll
  for (int mt=0;mt<2;mt++){
    float v = lp[mt];
    v += __shfl_xor(v, 16, 64);
    v += __shfl_xor(v, 32, 64);
    l[mt] = v;
  }

  // Epilogue: UNNORMALIZED bf16 partials, lane-packed [row][n16*8+dt]
  // (ch = dt*16+n16); one 16B store per (mt,r), 256B/quad contiguous.
  #pragma unroll
  for (int mt=0;mt<2;mt++){
    #pragma unroll
    for (int r=0;r<4;r++){
      __align__(16) u16 tmp[8];
      #pragma unroll
      for (int dt=0;dt<8;dt++) tmp[dt] = f2bf(o[mt][dt][r]);
      *(uint4*)(Os + (size_t)(q0 + mt*16 + quad*4 + r)*128 + n16*8) = *(uint4*)tmp;
    }
    if (lane < 16)
      ls[q0 + mt*16 + lane] = l[mt];
  }
}

// ---------------------------------------------------------------------------
// Kernel 3b: merge partials -> OmT in CONV layout [q][j], normalized bf16.
// 256 blocks x 32 attn rows so all CUs share the 32 MB reduction.
// attn row = b*1024 + j*8 + hwhi; stored col' encodes ch = (col'&7)*16 +
// (col'>>3); block covers 4 j values x all 1024 hw of one b -> 8B stores.
// ---------------------------------------------------------------------------
__global__ __launch_bounds__(256) void merge_o_kernel(
    const u16* __restrict__ Opart, const float* __restrict__ lpart, int S,
    u16* __restrict__ OmT)
{
  __shared__ u16 Tm[32][136];
  __shared__ float lrow[32];
  const int t = threadIdx.x;
  const int row0 = blockIdx.x * 32;
  const int b  = row0 >> 10;
  const int j0 = (row0 >> 3) & 127;

  if (t < 32){
    float v = 0.f;
    for (int sp=0; sp<S; sp++) v += lpart[sp*8192 + row0 + t];
    lrow[t] = 1.0f / v;
  }

  const int rl = t >> 3;            // 0..31
  const int cb = (t & 7) * 16;      // 0..112
  float acc[16];
  #pragma unroll
  for (int j=0;j<16;j++) acc[j] = 0.f;
  for (int sp=0; sp<S; sp++){
    const u16* p = Opart + (size_t)sp*1048576 + (size_t)(row0 + rl)*128 + cb;
    #pragma unroll
    for (int q=0;q<2;q++){
      ushort4 v = *(const ushort4*)(p + q*8);
      ushort4 w = *(const ushort4*)(p + q*8 + 4);
      acc[q*8+0] += bf2f(v.x); acc[q*8+1] += bf2f(v.y);
      acc[q*8+2] += bf2f(v.z); acc[q*8+3] += bf2f(v.w);
      acc[q*8+4] += bf2f(w.x); acc[q*8+5] += bf2f(w.y);
      acc[q*8+6] += bf2f(w.z); acc[q*8+7] += bf2f(w.w);
    }
  }
  __syncthreads();
  const float inv = lrow[rl];
  #pragma unroll
  for (int j=0;j<16;j++){
    int cp = cb + j;
    int ch = (cp & 7)*16 + (cp >> 3);
    Tm[rl][ch] = f2bf(acc[j] * inv);     // Tm[local attn row][ch]
  }
  __syncthreads();
  // conv-layout output: local row rl = jl*8 + hwhi  (jl = j - j0, 0..3)
  {
    const int hwhi = t >> 5;             // 0..7
    const int chb  = (t & 31) * 4;       // 4 ch per thread
    #pragma unroll
    for (int c=0;c<4;c++){
      int ch = chb + c;
      __align__(8) u16 tmp[4];
      #pragma unroll
      for (int jl=0;jl<4;jl++) tmp[jl] = Tm[jl*8 + hwhi][ch];
      *(uint2*)(OmT + (size_t)(b*1024 + hwhi*128 + ch)*128 + j0) = *(uint2*)tmp;
    }
  }
}

// ---------------------------------------------------------------------------
// Kernel 4: final conv as MFMA + bias + residual (fp32 out).
// D[co][q] = sum_j Ww[co][j] * OmT[q][j];  out = D + Wb + x.
// grid (4 co-tiles, 64 qg); block = 64co x 128q, K=128 single stage.
// ---------------------------------------------------------------------------
__global__ __launch_bounds__(256, 2) void final_mfma_kernel(
    const float* __restrict__ Ww, const float* __restrict__ Wb,
    const u16* __restrict__ OmT, const float* __restrict__ x,
    float* __restrict__ outp)
{
  __shared__ __align__(16) u16 Ws[64][136];
  __shared__ __align__(16) u16 Os[128][136];
  const int co0 = blockIdx.x * 64, qg = blockIdx.y;
  const int b = qg >> 3, hw0 = (qg & 7) * 128;
  const int q0 = qg * 128;                      // == b*1024 + hw0
  const int t = threadIdx.x;
  const int wave = t >> 6, lane = t & 63;
  const int quad = lane >> 4, n16 = lane & 15;

  {
    int row = t >> 2, cbf = (t & 3) * 32;
    const float* sw = Ww + (size_t)(co0 + row)*128 + cbf;
    #pragma unroll
    for (int i=0;i<8;i++){
      float4 v = *(const float4*)(sw + i*4);
      u16* d = &Ws[row][cbf + i*4];
      d[0]=f2bf(v.x); d[1]=f2bf(v.y); d[2]=f2bf(v.z); d[3]=f2bf(v.w);
    }
  }
  {
    int row = t >> 1, cb = (t & 1) * 64;
    const u16* so = OmT + (size_t)(q0 + row)*128 + cb;
    #pragma unroll
    for (int i=0;i<8;i++)
      *(uint4*)&Os[row][cb + i*8] = *(const uint4*)(so + i*8);
  }
  __syncthreads();

  f32x4 acc[4][2];
  #pragma unroll
  for (int mt=0;mt<4;mt++)
    #pragma unroll
    for (int nt=0;nt<2;nt++){ f32x4 z = {0.f,0.f,0.f,0.f}; acc[mt][nt] = z; }

  #pragma unroll
  for (int kc=0; kc<4; kc++){
    short8 xf[2];
    #pragma unroll
    for (int nt=0;nt<2;nt++)
      xf[nt] = *(const short8*)&Os[wave*32 + nt*16 + n16][kc*32 + quad*8];
    #pragma unroll
    for (int mt=0;mt<4;mt++){
      short8 wf = *(const short8*)&Ws[mt*16 + n16][kc*32 + quad*8];
      #pragma unroll
      for (int nt=0;nt<2;nt++)
        acc[mt][nt] = __builtin_amdgcn_mfma_f32_16x16x32_bf16(wf, xf[nt], acc[mt][nt], 0, 0, 0);
    }
  }

  #pragma unroll
  for (int mt=0;mt<4;mt++){
    float4 bv = *(const float4*)&Wb[co0 + mt*16 + quad*4];
    float bb[4] = {bv.x, bv.y, bv.z, bv.w};
    #pragma unroll
    for (int nt=0;nt<2;nt++)
      #pragma unroll
      for (int r=0;r<4;r++){
        size_t idx = (size_t)b*262144 + (size_t)(co0 + mt*16 + quad*4 + r)*1024
                   + hw0 + wave*32 + nt*16 + n16;
        outp[idx] = acc[mt][nt][r] + bb[r] + x[idx];
      }
  }
}

// ---------------------------------------------------------------------------
extern "C" void kernel_launch(void* const* d_in, const int* in_sizes, int n_in,
                              void* d_out, int out_size, void* d_ws, size_t ws_size,
                              hipStream_t stream)
{
  (void)in_sizes; (void)n_in; (void)out_size; (void)ws_size;
  const float* x  = (const float*)d_in[0];
  const float* tw = (const float*)d_in[1];
  const float* tb = (const float*)d_in[2];
  const float* pw = (const float*)d_in[3];
  const float* pb = (const float*)d_in[4];
  const float* gw = (const float*)d_in[5];
  const float* gb = (const float*)d_in[6];
  const float* Ww = (const float*)d_in[7];
  const float* Wb = (const float*)d_in[8];
  float* outp = (float*)d_out;

  char* ws = (char*)d_ws;
  const size_t MB = 1u << 20;
  u16*   Tbf   = (u16*)(ws);            // 2 MB  theta bf16 (log2e-scaled), conv-flat
  u16*   PHIbf = (u16*)(ws + 2*MB);     // 2 MB  phi, conv-flat
  u16*   Gbf   = (u16*)(ws + 4*MB);     // 2 MB  g, conv-flat
  u16*   Kbf   = (u16*)(ws + 6*MB);     // 2 MB  K = phi^T  [8192][128]
  u16*   VTbf  = (u16*)(ws + 8*MB);     // 2 MB  VT = g^T   [128][8192]
  // Lifetime overlays (ws >= 43 MB proven by earlier S=16 runs):
  u16*   Opart = (u16*)(ws + 10*MB);    // 16 x 2 MB bf16 partials (attn+)
  u16*   XT    = (u16*)(ws + 10*MB);    // 4 MB x^T bf16 (dead before attn)
  float* lpart = (float*)(ws + 2*MB);   // 512 KB (PHI dead after transpose)
  u16*   OmT   = (u16*)(ws + 4*MB);     // 2 MB merged O (Gbf dead after transpose)

  xcast_kernel<<<dim3(16, 4, 8), 256, 0, stream>>>(x, XT);
  proj_mfma_kernel<<<dim3(3, 64), 256, 0, stream>>>(XT, tw, pw, gw, tb, pb, gb,
                                                    Tbf, PHIbf, Gbf);
  transpose_bf_kernel<<<dim3(128, 2), 256, 0, stream>>>(PHIbf, Kbf, 128, 8192);
  transpose_bf_kernel<<<dim3(2, 128), 256, 0, stream>>>(Gbf, VTbf, 8192, 128);
  attn_kernel<<<dim3(1024), 256, 0, stream>>>(Tbf, Kbf, VTbf, Opart, lpart);
  merge_o_kernel<<<dim3(256), 256, 0, stream>>>(Opart, lpart, 16, OmT);
  final_mfma_kernel<<<dim3(4, 64), 256, 0, stream>>>(Ww, Wb, OmT, x, outp);
}